// Round 13
// baseline (37.073 us; speedup 1.0000x reference)
//
#include <hip/hip_runtime.h>
#include <math.h>

// ExpLogDiceLoss: N x 32 fp32 scores, int32 labels -> scalar loss.
//
// loss_c = pow( log((counts_c + npr_sum_c) / (2 * ni_sum_c)), 0.3 ) for present c
// out = sum_c loss_c / n_present
// where npr_sum_c = sum_rows softmax(score[row])[c]
//       ni_sum_c  = sum_{rows: label==c} softmax(score[row])[c]
//
// TWO dispatches (R5/R9/R11: fusion loses; R12: a 3rd dispatch costs ~5us).
// Pass1: 1024 blocks x 256 threads (4 blocks/CU, 16 waves/CU), class-major
// partials [96][1024] = 393 KB.
// Pass2 (fused tail, 1 block x 1024 threads): 16 waves x 6 contiguous 4KB
// rows, 4 unrolled float4 loads/lane/row (parallel, no latency chain),
// wave shfl row-sums -> 96 LDS totals -> wave 0: per-class loss + scalar.
// All fixed-order, deterministic; no atomics.

#define NBLK1 1024
#define NTHR1 256

__global__ __launch_bounds__(NTHR1) void eld_pass1(
    const float* __restrict__ score, const int* __restrict__ label,
    float* __restrict__ part,   // [96][nblk] class-major
    int nrows, int ngroups, int nblk)
{
    const int tid   = threadIdx.x;
    const int q     = tid & 7;     // column quarter: classes [4q, 4q+4)
    const int rslot = tid >> 3;    // row slot within a 32-row group
    const int cbase = q << 2;

    float a_npr0 = 0.f, a_npr1 = 0.f, a_npr2 = 0.f, a_npr3 = 0.f;
    float a_ni0  = 0.f, a_ni1  = 0.f, a_ni2  = 0.f, a_ni3  = 0.f;
    float a_c0   = 0.f, a_c1   = 0.f, a_c2   = 0.f, a_c3   = 0.f;

    for (int g = blockIdx.x; g < ngroups; g += gridDim.x) {
        const int row = g * 32 + rslot;
        if (row < nrows) {
            const float4 v = reinterpret_cast<const float4*>(score)[row * 8 + q];
            // row max across 32 classes (8 lanes x 4 elems)
            float m = fmaxf(fmaxf(v.x, v.y), fmaxf(v.z, v.w));
            m = fmaxf(m, __shfl_xor(m, 1));
            m = fmaxf(m, __shfl_xor(m, 2));
            m = fmaxf(m, __shfl_xor(m, 4));
            const float e0 = __expf(v.x - m);
            const float e1 = __expf(v.y - m);
            const float e2 = __expf(v.z - m);
            const float e3 = __expf(v.w - m);
            float s = (e0 + e1) + (e2 + e3);
            s += __shfl_xor(s, 1);
            s += __shfl_xor(s, 2);
            s += __shfl_xor(s, 4);
            const float inv = __builtin_amdgcn_rcpf(s);  // s >= 1, ~1 ulp
            const float p0 = e0 * inv, p1 = e1 * inv, p2 = e2 * inv, p3 = e3 * inv;
            a_npr0 += p0; a_npr1 += p1; a_npr2 += p2; a_npr3 += p3;
            const int lab = label[row];
            // static-indexed predicated accumulate (avoid runtime-indexed arrays)
            if (lab == cbase + 0) { a_ni0 += p0; a_c0 += 1.f; }
            if (lab == cbase + 1) { a_ni1 += p1; a_c1 += 1.f; }
            if (lab == cbase + 2) { a_ni2 += p2; a_c2 += 1.f; }
            if (lab == cbase + 3) { a_ni3 += p3; a_c3 += 1.f; }
        }
    }

    // reduce across the 8 row-slots of each wave (lanes with equal (lane&7))
#pragma unroll
    for (int off = 8; off < 64; off <<= 1) {
        a_npr0 += __shfl_xor(a_npr0, off);
        a_npr1 += __shfl_xor(a_npr1, off);
        a_npr2 += __shfl_xor(a_npr2, off);
        a_npr3 += __shfl_xor(a_npr3, off);
        a_ni0  += __shfl_xor(a_ni0,  off);
        a_ni1  += __shfl_xor(a_ni1,  off);
        a_ni2  += __shfl_xor(a_ni2,  off);
        a_ni3  += __shfl_xor(a_ni3,  off);
        a_c0   += __shfl_xor(a_c0,   off);
        a_c1   += __shfl_xor(a_c1,   off);
        a_c2   += __shfl_xor(a_c2,   off);
        a_c3   += __shfl_xor(a_c3,   off);
    }

    __shared__ float lds[3][4][32];
    const int wave = tid >> 6;
    const int lane = tid & 63;
    if (lane < 8) {
        lds[0][wave][lane * 4 + 0] = a_npr0;
        lds[0][wave][lane * 4 + 1] = a_npr1;
        lds[0][wave][lane * 4 + 2] = a_npr2;
        lds[0][wave][lane * 4 + 3] = a_npr3;
        lds[1][wave][lane * 4 + 0] = a_ni0;
        lds[1][wave][lane * 4 + 1] = a_ni1;
        lds[1][wave][lane * 4 + 2] = a_ni2;
        lds[1][wave][lane * 4 + 3] = a_ni3;
        lds[2][wave][lane * 4 + 0] = a_c0;
        lds[2][wave][lane * 4 + 1] = a_c1;
        lds[2][wave][lane * 4 + 2] = a_c2;
        lds[2][wave][lane * 4 + 3] = a_c3;
    }
    __syncthreads();
    if (tid < 32) {
        float n = 0.f, i2 = 0.f, k = 0.f;
#pragma unroll
        for (int w = 0; w < 4; ++w) {
            n  += lds[0][w][tid];
            i2 += lds[1][w][tid];
            k  += lds[2][w][tid];
        }
        // class-major scatter: contiguous per-class rows for pass2
        part[(size_t)tid * nblk + blockIdx.x]        = n;
        part[(size_t)(32 + tid) * nblk + blockIdx.x] = i2;
        part[(size_t)(64 + tid) * nblk + blockIdx.x] = k;
    }
}

// Fused tail: one block, 1024 threads (16 waves). Wave w reduces rows
// 6w..6w+5 (each row = nblk contiguous floats); 96 row-totals in LDS;
// wave 0 computes the 32 class losses and the final scalar.
__global__ __launch_bounds__(1024) void eld_pass2(
    const float* __restrict__ part, float* __restrict__ out, int nblk)
{
    __shared__ float rowsum[96];
    __shared__ float result;
    const int tid  = threadIdx.x;
    const int wave = tid >> 6;     // 0..15
    const int lane = tid & 63;

#pragma unroll
    for (int i = 0; i < 6; ++i) {
        const int r = wave * 6 + i;
        const float* row = part + (size_t)r * nblk;
        float acc = 0.f;
        if (nblk == NBLK1) {
            // 1024 floats = 256 float4; 64 lanes x 4 unrolled float4 loads
            const float4* row4 = reinterpret_cast<const float4*>(row);
            float4 v0 = row4[lane];
            float4 v1 = row4[lane + 64];
            float4 v2 = row4[lane + 128];
            float4 v3 = row4[lane + 192];
            acc = ((v0.x + v0.y) + (v0.z + v0.w)) + ((v1.x + v1.y) + (v1.z + v1.w))
                + ((v2.x + v2.y) + (v2.z + v2.w)) + ((v3.x + v3.y) + (v3.z + v3.w));
        } else {
            for (int e = lane; e < nblk; e += 64) acc += row[e];
        }
#pragma unroll
        for (int off = 1; off < 64; off <<= 1) acc += __shfl_xor(acc, off);
        if (lane == 0) rowsum[r] = acc;
    }
    __syncthreads();

    if (wave == 0) {
        float loss = 0.f, pres = 0.f;
        if (lane < 32) {
            const float N_ = rowsum[lane];
            const float I  = rowsum[32 + lane];
            const float K  = rowsum[64 + lane];
            if (K > 0.f) {
                float nld = logf((K + N_) / (2.f * I));   // >= 0 by construction
                nld = fmaxf(nld, 0.f);
                loss = powf(nld, 0.3f);
                pres = 1.f;
            }
        }
#pragma unroll
        for (int off = 1; off < 64; off <<= 1) {
            loss += __shfl_xor(loss, off);
            pres += __shfl_xor(pres, off);
        }
        if (lane == 0) result = loss / pres;   // LOSS_WEIGHT = 1
    }
    __syncthreads();
    if (tid == 0) out[0] = result;
}

extern "C" void kernel_launch(void* const* d_in, const int* in_sizes, int n_in,
                              void* d_out, int out_size, void* d_ws, size_t ws_size,
                              hipStream_t stream) {
    const float* score = (const float*)d_in[0];
    const int*   label = (const int*)d_in[1];
    float* out = (float*)d_out;

    const int nrows = in_sizes[0] / 32;
    const int ngroups = (nrows + 31) / 32;

    int nblk = NBLK1;
    if (nblk > ngroups) nblk = ngroups;

    float* part = (float*)d_ws;   // [96 * nblk]

    eld_pass1<<<nblk, NTHR1, 0, stream>>>(score, label, part, nrows, ngroups, nblk);
    eld_pass2<<<1, 1024, 0, stream>>>(part, out, nblk);
}